// Round 14
// baseline (82.484 us; speedup 1.0000x reference)
//
#include <hip/hip_runtime.h>
#include <hip/hip_bf16.h>

#define B_   4096
#define S_   32
#define IN_  256
#define H_   128
#define OUT_ 256

typedef __attribute__((ext_vector_type(8))) short bf16x8;
typedef __attribute__((ext_vector_type(4))) float f32x4;
typedef unsigned long long ull;

__device__ __forceinline__ unsigned short f2bf(float f) {
    union { float f; unsigned u; } v; v.f = f;
    unsigned r = v.u + 0x7FFFu + ((v.u >> 16) & 1u);   // RNE
    return (unsigned short)(r >> 16);
}
__device__ __forceinline__ unsigned cvt_pk(float lo, float hi) {
    unsigned r;
    asm("v_cvt_pk_bf16_f32 %0, %1, %2" : "=v"(r) : "v"(lo), "v"(hi));
    return r;
}

// pack_w1: W1 [S][IN(k)][H] f32 -> fragment-major bf16 A1 frags.
// w1f[s][kk=8][hf=8][lane=64][8]: lane: h-row = hf*16 + (l&15), k = kk*32 + (l>>4)*8 + j.
__global__ __launch_bounds__(256) void pack_w1(const float* __restrict__ W1,
                                               unsigned short* __restrict__ w1f) {
    __shared__ float tile[32][129];
    const int bid = blockIdx.x, s = bid >> 3, kk = bid & 7;
    const int t = threadIdx.x;
#pragma unroll
    for (int i = 0; i < 16; ++i) {
        int idx = t + i * 256;
        int kl = idx >> 7, h = idx & 127;
        tile[kl][h] = W1[((size_t)s * IN_ + kk * 32 + kl) * H_ + h];
    }
    __syncthreads();
#pragma unroll
    for (int rep = 0; rep < 2; ++rep) {
        int idx = t + rep * 256;
        int hf = idx >> 6, l = idx & 63, l15 = l & 15, l4 = l >> 4;
        unsigned short o8[8];
#pragma unroll
        for (int j = 0; j < 8; ++j) o8[j] = f2bf(tile[l4 * 8 + j][hf * 16 + l15]);
        *(bf16x8*)(w1f + (((size_t)(s * 8 + kk) * 8 + hf) * 64 + l) * 8) = *(bf16x8*)o8;
    }
}

// pack_w2: W2 [S][H(k)][OUT] f32 -> fragment-major bf16 A2 frags (swapped L2).
// w2f[s][g=16][kkh=4][lane=64][8]: lane: o-row = g*16 + (l&15), h = kkh*32 + (l>>4)*8 + j.
__global__ __launch_bounds__(256) void pack_w2(const float* __restrict__ W2,
                                               unsigned short* __restrict__ w2f) {
    __shared__ float tile[32][257];
    const int bid = blockIdx.x, s = bid >> 2, kkh = bid & 3;
    const int t = threadIdx.x;
#pragma unroll
    for (int i = 0; i < 32; ++i) {
        int idx = t + i * 256;
        int kl = idx >> 8, o = idx & 255;
        tile[kl][o] = W2[((size_t)s * H_ + kkh * 32 + kl) * OUT_ + o];
    }
    __syncthreads();
#pragma unroll
    for (int rep = 0; rep < 4; ++rep) {
        int idx = t + rep * 256;
        int g = idx >> 6, l = idx & 63, l15 = l & 15, l4 = l >> 4;
        unsigned short o8[8];
#pragma unroll
        for (int j = 0; j < 8; ++j) o8[j] = f2bf(tile[l4 * 8 + j][g * 16 + l15]);
        *(bf16x8*)(w2f + (((size_t)(s * 16 + g) * 4 + kkh) * 64 + l) * 8) = *(bf16x8*)o8;
    }
}

// Weights-stationary fused MLP, fragment-major LDS.
// R14 change vs R13 (single variable): tile-top wait is COUNTED — vmcnt(16)
// for t>0 retires this tile's 16 x-loads but leaves the previous tile's 16
// stores in flight (never drained mid-kernel). FIFO at tile top is exactly
// [16 x-loads oldest, 16 stores newest]; all other VMEM retired pre-barrier.
__global__ __launch_bounds__(512) void subband_fused_kernel(
        const float* __restrict__ x,
        const unsigned short* __restrict__ w1f,
        const unsigned short* __restrict__ w2f,
        const float* __restrict__ b1,
        const float* __restrict__ b2,
        float* __restrict__ out) {
    __shared__ __align__(16) unsigned char lds[161280];
    unsigned char* w1l = lds;
    unsigned char* w2l = lds + 65536;
    unsigned char* repb = lds + 126976;
    float* b1l = (float*)(lds + 159744);
    float* b2l = (float*)(lds + 160256);

    const int bid = blockIdx.x;
    const int s   = bid & 31;
    const int chunk = bid >> 5;
    const int tid = threadIdx.x;
    const int w = tid >> 6, l = tid & 63, l15 = l & 15, l4 = l >> 4;
    unsigned char* rep = repb + w * 4096;
    const int rw = chunk * 512 + w * 64;

#define LDG(dst, p) asm volatile("global_load_dwordx4 %0, %1, off" : "=v"(dst) : "v"(p))

    // ---- issue tile-0 x loads first ----
    f32x4 v[16];
    {
        const float* xr = x + ((size_t)(rw + l15) * S_ + s) * IN_ + l4 * 8;
#pragma unroll
        for (int kk = 0; kk < 8; ++kk) {
            LDG(v[2 * kk],     xr + kk * 32);
            LDG(v[2 * kk + 1], xr + kk * 32 + 4);
        }
    }

    // ---- stage weights: linear coalesced copies ----
    const unsigned char* w1src = (const unsigned char*)(w1f + (size_t)s * 32768);
#pragma unroll
    for (int i = 0; i < 8; ++i)
        *(bf16x8*)(w1l + tid * 16 + i * 8192) = *(const bf16x8*)(w1src + tid * 16 + i * 8192);
    const unsigned char* w2src = (const unsigned char*)(w2f + (size_t)s * 32768);
#pragma unroll
    for (int i = 0; i < 7; ++i)
        *(bf16x8*)(w2l + tid * 16 + i * 8192) = *(const bf16x8*)(w2src + tid * 16 + i * 8192);
    if (tid < 256)
        *(bf16x8*)(w2l + tid * 16 + 57344) = *(const bf16x8*)(w2src + tid * 16 + 57344);

    bf16x8 w2r[4];
#pragma unroll
    for (int kkh = 0; kkh < 4; ++kkh)
        w2r[kkh] = *(const bf16x8*)(w2src + (((size_t)15 * 4 + kkh) * 64 + l) * 16);

    if (tid < 128)      b1l[tid]       = b1[s * H_ + tid];
    else if (tid < 384) b2l[tid - 128] = b2[s * OUT_ + (tid - 128)];

    __syncthreads();                           // the ONLY barrier

    float* opbase = out + ((size_t)(rw + l15) * S_ + s) * OUT_;

#pragma unroll 1
    for (int t = 0; t < 4; ++t) {
        // ---- tile-top wait: COUNTED. t=0 drains all; t>0 leaves 16 stores in flight ----
        if (t == 0) {
            asm volatile("s_waitcnt vmcnt(0)"
                : "+v"(v[0]), "+v"(v[1]), "+v"(v[2]), "+v"(v[3]),
                  "+v"(v[4]), "+v"(v[5]), "+v"(v[6]), "+v"(v[7]),
                  "+v"(v[8]), "+v"(v[9]), "+v"(v[10]), "+v"(v[11]),
                  "+v"(v[12]), "+v"(v[13]), "+v"(v[14]), "+v"(v[15]) :: "memory");
        } else {
            asm volatile("s_waitcnt vmcnt(16)"
                : "+v"(v[0]), "+v"(v[1]), "+v"(v[2]), "+v"(v[3]),
                  "+v"(v[4]), "+v"(v[5]), "+v"(v[6]), "+v"(v[7]),
                  "+v"(v[8]), "+v"(v[9]), "+v"(v[10]), "+v"(v[11]),
                  "+v"(v[12]), "+v"(v[13]), "+v"(v[14]), "+v"(v[15]) :: "memory");
        }
        __builtin_amdgcn_sched_barrier(0);

        // ---- convert to B-fragments: lane m = l15, k = kk*32 + l4*8 + j ----
        bf16x8 xb[8];
#pragma unroll
        for (int kk = 0; kk < 8; ++kk) {
            union { unsigned u[4]; bf16x8 b; } p;
            p.u[0] = cvt_pk(v[2 * kk][0],     v[2 * kk][1]);
            p.u[1] = cvt_pk(v[2 * kk][2],     v[2 * kk][3]);
            p.u[2] = cvt_pk(v[2 * kk + 1][0], v[2 * kk + 1][1]);
            p.u[3] = cvt_pk(v[2 * kk + 1][2], v[2 * kk + 1][3]);
            xb[kk] = p.b;
        }

        // ---- issue next tile's x loads ----
        if (t < 3) {
            const float* xr = x + ((size_t)(rw + (t + 1) * 16 + l15) * S_ + s) * IN_ + l4 * 8;
#pragma unroll
            for (int kk = 0; kk < 8; ++kk) {
                LDG(v[2 * kk],     xr + kk * 32);
                LDG(v[2 * kk + 1], xr + kk * 32 + 4);
            }
        }

        // ---- layer 1 swapped: acc1[hf] holds h = hf*16 + l4*4 + i, m = l15 ----
        f32x4 acc1[8];
#pragma unroll
        for (int hf = 0; hf < 8; ++hf) {
            const float4 bv = *(const float4*)(b1l + hf * 16 + l4 * 4);
            acc1[hf][0] = bv.x; acc1[hf][1] = bv.y; acc1[hf][2] = bv.z; acc1[hf][3] = bv.w;
        }
#pragma unroll
        for (int kk = 0; kk < 8; ++kk)
#pragma unroll
            for (int hf = 0; hf < 8; ++hf) {
                const bf16x8 wf = *(const bf16x8*)(w1l + ((kk * 8 + hf) * 64 + l) * 16);
                acc1[hf] = __builtin_amdgcn_mfma_f32_16x16x32_bf16(wf, xb[kk], acc1[hf], 0, 0, 0);
            }

        // ---- relu + repack -> fragment-major rep ----
#pragma unroll
        for (int hf = 0; hf < 8; ++hf) {
            unsigned p0 = cvt_pk(fmaxf(acc1[hf][0], 0.f), fmaxf(acc1[hf][1], 0.f));
            unsigned p1 = cvt_pk(fmaxf(acc1[hf][2], 0.f), fmaxf(acc1[hf][3], 0.f));
            ull p = (ull)p0 | ((ull)p1 << 32);
            const int kkh = hf >> 1;
            const int l4p = ((hf & 1) << 1) | (l4 >> 1);
            *(ull*)(rep + kkh * 1024 + (l4p * 16 + l15) * 16 + ((l4 & 1) * 8)) = p;
        }
        asm volatile("s_waitcnt lgkmcnt(0)" ::: "memory");
        __builtin_amdgcn_sched_barrier(0);

        bf16x8 hfr[4];
#pragma unroll
        for (int kkh = 0; kkh < 4; ++kkh)
            hfr[kkh] = *(const bf16x8*)(rep + kkh * 1024 + l * 16);

        // ---- layer 2 swapped: D2[o][m]; o = g*16 + l4*4 + i, m = l15 ----
        float* op = opbase + (size_t)t * 16 * S_ * OUT_;
#pragma unroll
        for (int g = 0; g < 16; ++g) {
            const float4 bv = *(const float4*)(b2l + g * 16 + l4 * 4);
            f32x4 acc2;
            acc2[0] = bv.x; acc2[1] = bv.y; acc2[2] = bv.z; acc2[3] = bv.w;
#pragma unroll
            for (int kkh = 0; kkh < 4; ++kkh) {
                const bf16x8 wf = (g < 15)
                    ? *(const bf16x8*)(w2l + ((g * 4 + kkh) * 64 + l) * 16)
                    : w2r[kkh];
                acc2 = __builtin_amdgcn_mfma_f32_16x16x32_bf16(wf, hfr[kkh], acc2, 0, 0, 0);
            }
            *(f32x4*)(op + g * 16 + l4 * 4) = acc2;   // fire-and-forget
        }
    }
#undef LDG
}

extern "C" void kernel_launch(void* const* d_in, const int* in_sizes, int n_in,
                              void* d_out, int out_size, void* d_ws, size_t ws_size,
                              hipStream_t stream) {
    const float* x  = (const float*)d_in[0];
    const float* W1 = (const float*)d_in[1];
    const float* b1 = (const float*)d_in[2];
    const float* W2 = (const float*)d_in[3];
    const float* b2 = (const float*)d_in[4];
    float* out = (float*)d_out;

    unsigned short* w1f = (unsigned short*)d_ws;                 // 2 MiB
    unsigned short* w2f = w1f + (size_t)S_ * 8 * 8 * 64 * 8;     // 2 MiB (total = 4 MiB)

    pack_w1<<<S_ * 8, 256, 0, stream>>>(W1, w1f);
    pack_w2<<<S_ * 4, 256, 0, stream>>>(W2, w2f);
    subband_fused_kernel<<<256, 512, 0, stream>>>(x, w1f, w2f, b1, b2, out);
}

// Round 15
// 72.501 us; speedup vs baseline: 1.1377x; 1.1377x over previous
//
#include <hip/hip_runtime.h>
#include <hip/hip_bf16.h>

#define B_   4096
#define S_   32
#define IN_  256
#define H_   128
#define OUT_ 256

typedef __attribute__((ext_vector_type(8))) short bf16x8;
typedef __attribute__((ext_vector_type(4))) float f32x4;
typedef unsigned long long ull;

__device__ __forceinline__ unsigned short f2bf(float f) {
    union { float f; unsigned u; } v; v.f = f;
    unsigned r = v.u + 0x7FFFu + ((v.u >> 16) & 1u);   // RNE
    return (unsigned short)(r >> 16);
}
__device__ __forceinline__ unsigned cvt_pk(float lo, float hi) {
    unsigned r;
    asm("v_cvt_pk_bf16_f32 %0, %1, %2" : "=v"(r) : "v"(lo), "v"(hi));
    return r;
}

// pack_w1: W1 [S][IN(k)][H] f32 -> fragment-major bf16 A1 frags.
// w1f[s][kk=8][hf=8][lane=64][8]: lane: h-row = hf*16 + (l&15), k = kk*32 + (l>>4)*8 + j.
__global__ __launch_bounds__(256) void pack_w1(const float* __restrict__ W1,
                                               unsigned short* __restrict__ w1f) {
    __shared__ float tile[32][129];
    const int bid = blockIdx.x, s = bid >> 3, kk = bid & 7;
    const int t = threadIdx.x;
#pragma unroll
    for (int i = 0; i < 16; ++i) {
        int idx = t + i * 256;
        int kl = idx >> 7, h = idx & 127;
        tile[kl][h] = W1[((size_t)s * IN_ + kk * 32 + kl) * H_ + h];
    }
    __syncthreads();
#pragma unroll
    for (int rep = 0; rep < 2; ++rep) {
        int idx = t + rep * 256;
        int hf = idx >> 6, l = idx & 63, l15 = l & 15, l4 = l >> 4;
        unsigned short o8[8];
#pragma unroll
        for (int j = 0; j < 8; ++j) o8[j] = f2bf(tile[l4 * 8 + j][hf * 16 + l15]);
        *(bf16x8*)(w1f + (((size_t)(s * 8 + kk) * 8 + hf) * 64 + l) * 8) = *(bf16x8*)o8;
    }
}

// pack_w2: W2 [S][H(k)][OUT] f32 -> fragment-major bf16 A2 frags (swapped L2).
// w2f[s][g=16][kkh=4][lane=64][8]: lane: o-row = g*16 + (l&15), h = kkh*32 + (l>>4)*8 + j.
__global__ __launch_bounds__(256) void pack_w2(const float* __restrict__ W2,
                                               unsigned short* __restrict__ w2f) {
    __shared__ float tile[32][257];
    const int bid = blockIdx.x, s = bid >> 2, kkh = bid & 3;
    const int t = threadIdx.x;
#pragma unroll
    for (int i = 0; i < 32; ++i) {
        int idx = t + i * 256;
        int kl = idx >> 8, o = idx & 255;
        tile[kl][o] = W2[((size_t)s * H_ + kkh * 32 + kl) * OUT_ + o];
    }
    __syncthreads();
#pragma unroll
    for (int rep = 0; rep < 4; ++rep) {
        int idx = t + rep * 256;
        int g = idx >> 6, l = idx & 63, l15 = l & 15, l4 = l >> 4;
        unsigned short o8[8];
#pragma unroll
        for (int j = 0; j < 8; ++j) o8[j] = f2bf(tile[l4 * 8 + j][g * 16 + l15]);
        *(bf16x8*)(w2f + (((size_t)(s * 16 + g) * 4 + kkh) * 64 + l) * 8) = *(bf16x8*)o8;
    }
}

// Weights-stationary fused MLP, fragment-major LDS.
// R15 change vs R13 (single variable): bid decomposition swapped so that
// bid%8 (the XCD id) = row-chunk, not subband. Each XCD's 32 blocks cover
// ALL 32 subbands of ONE contiguous 512-row window -> the XCD's aggregate
// HBM read/write stream is a dense contiguous 16 MB region (DRAM row-buffer
// friendly) instead of 64B granules scattered across the full 128 MB.
__global__ __launch_bounds__(512) void subband_fused_kernel(
        const float* __restrict__ x,
        const unsigned short* __restrict__ w1f,
        const unsigned short* __restrict__ w2f,
        const float* __restrict__ b1,
        const float* __restrict__ b2,
        float* __restrict__ out) {
    __shared__ __align__(16) unsigned char lds[161280];
    unsigned char* w1l = lds;
    unsigned char* w2l = lds + 65536;
    unsigned char* repb = lds + 126976;
    float* b1l = (float*)(lds + 159744);
    float* b2l = (float*)(lds + 160256);

    const int bid = blockIdx.x;
    const int s     = bid >> 3;                // subband (32)
    const int chunk = bid & 7;                 // row-chunk == XCD id
    const int tid = threadIdx.x;
    const int w = tid >> 6, l = tid & 63, l15 = l & 15, l4 = l >> 4;
    unsigned char* rep = repb + w * 4096;
    const int rw = chunk * 512 + w * 64;       // wave's 64 rows

#define LDG(dst, p) asm volatile("global_load_dwordx4 %0, %1, off" : "=v"(dst) : "v"(p))

    // ---- issue tile-0 x loads first ----
    f32x4 v[16];
    {
        const float* xr = x + ((size_t)(rw + l15) * S_ + s) * IN_ + l4 * 8;
#pragma unroll
        for (int kk = 0; kk < 8; ++kk) {
            LDG(v[2 * kk],     xr + kk * 32);
            LDG(v[2 * kk + 1], xr + kk * 32 + 4);
        }
    }

    // ---- stage weights: linear coalesced copies ----
    const unsigned char* w1src = (const unsigned char*)(w1f + (size_t)s * 32768);
#pragma unroll
    for (int i = 0; i < 8; ++i)
        *(bf16x8*)(w1l + tid * 16 + i * 8192) = *(const bf16x8*)(w1src + tid * 16 + i * 8192);
    const unsigned char* w2src = (const unsigned char*)(w2f + (size_t)s * 32768);
#pragma unroll
    for (int i = 0; i < 7; ++i)
        *(bf16x8*)(w2l + tid * 16 + i * 8192) = *(const bf16x8*)(w2src + tid * 16 + i * 8192);
    if (tid < 256)
        *(bf16x8*)(w2l + tid * 16 + 57344) = *(const bf16x8*)(w2src + tid * 16 + 57344);

    bf16x8 w2r[4];
#pragma unroll
    for (int kkh = 0; kkh < 4; ++kkh)
        w2r[kkh] = *(const bf16x8*)(w2src + (((size_t)15 * 4 + kkh) * 64 + l) * 16);

    if (tid < 128)      b1l[tid]       = b1[s * H_ + tid];
    else if (tid < 384) b2l[tid - 128] = b2[s * OUT_ + (tid - 128)];

    __syncthreads();                           // the ONLY barrier

    float* opbase = out + ((size_t)(rw + l15) * S_ + s) * OUT_;

#pragma unroll 1
    for (int t = 0; t < 4; ++t) {
        // ---- tile-top wait (R13-proven full drain) ----
        asm volatile("s_waitcnt vmcnt(0)"
            : "+v"(v[0]), "+v"(v[1]), "+v"(v[2]), "+v"(v[3]),
              "+v"(v[4]), "+v"(v[5]), "+v"(v[6]), "+v"(v[7]),
              "+v"(v[8]), "+v"(v[9]), "+v"(v[10]), "+v"(v[11]),
              "+v"(v[12]), "+v"(v[13]), "+v"(v[14]), "+v"(v[15]) :: "memory");
        __builtin_amdgcn_sched_barrier(0);

        // ---- convert to B-fragments: lane m = l15, k = kk*32 + l4*8 + j ----
        bf16x8 xb[8];
#pragma unroll
        for (int kk = 0; kk < 8; ++kk) {
            union { unsigned u[4]; bf16x8 b; } p;
            p.u[0] = cvt_pk(v[2 * kk][0],     v[2 * kk][1]);
            p.u[1] = cvt_pk(v[2 * kk][2],     v[2 * kk][3]);
            p.u[2] = cvt_pk(v[2 * kk + 1][0], v[2 * kk + 1][1]);
            p.u[3] = cvt_pk(v[2 * kk + 1][2], v[2 * kk + 1][3]);
            xb[kk] = p.b;
        }

        // ---- issue next tile's x loads ----
        if (t < 3) {
            const float* xr = x + ((size_t)(rw + (t + 1) * 16 + l15) * S_ + s) * IN_ + l4 * 8;
#pragma unroll
            for (int kk = 0; kk < 8; ++kk) {
                LDG(v[2 * kk],     xr + kk * 32);
                LDG(v[2 * kk + 1], xr + kk * 32 + 4);
            }
        }

        // ---- layer 1 swapped: acc1[hf] holds h = hf*16 + l4*4 + i, m = l15 ----
        f32x4 acc1[8];
#pragma unroll
        for (int hf = 0; hf < 8; ++hf) {
            const float4 bv = *(const float4*)(b1l + hf * 16 + l4 * 4);
            acc1[hf][0] = bv.x; acc1[hf][1] = bv.y; acc1[hf][2] = bv.z; acc1[hf][3] = bv.w;
        }
#pragma unroll
        for (int kk = 0; kk < 8; ++kk)
#pragma unroll
            for (int hf = 0; hf < 8; ++hf) {
                const bf16x8 wf = *(const bf16x8*)(w1l + ((kk * 8 + hf) * 64 + l) * 16);
                acc1[hf] = __builtin_amdgcn_mfma_f32_16x16x32_bf16(wf, xb[kk], acc1[hf], 0, 0, 0);
            }

        // ---- relu + repack -> fragment-major rep ----
#pragma unroll
        for (int hf = 0; hf < 8; ++hf) {
            unsigned p0 = cvt_pk(fmaxf(acc1[hf][0], 0.f), fmaxf(acc1[hf][1], 0.f));
            unsigned p1 = cvt_pk(fmaxf(acc1[hf][2], 0.f), fmaxf(acc1[hf][3], 0.f));
            ull p = (ull)p0 | ((ull)p1 << 32);
            const int kkh = hf >> 1;
            const int l4p = ((hf & 1) << 1) | (l4 >> 1);
            *(ull*)(rep + kkh * 1024 + (l4p * 16 + l15) * 16 + ((l4 & 1) * 8)) = p;
        }
        asm volatile("s_waitcnt lgkmcnt(0)" ::: "memory");
        __builtin_amdgcn_sched_barrier(0);

        bf16x8 hfr[4];
#pragma unroll
        for (int kkh = 0; kkh < 4; ++kkh)
            hfr[kkh] = *(const bf16x8*)(rep + kkh * 1024 + l * 16);

        // ---- layer 2 swapped: D2[o][m]; o = g*16 + l4*4 + i, m = l15 ----
        float* op = opbase + (size_t)t * 16 * S_ * OUT_;
#pragma unroll
        for (int g = 0; g < 16; ++g) {
            const float4 bv = *(const float4*)(b2l + g * 16 + l4 * 4);
            f32x4 acc2;
            acc2[0] = bv.x; acc2[1] = bv.y; acc2[2] = bv.z; acc2[3] = bv.w;
#pragma unroll
            for (int kkh = 0; kkh < 4; ++kkh) {
                const bf16x8 wf = (g < 15)
                    ? *(const bf16x8*)(w2l + ((g * 4 + kkh) * 64 + l) * 16)
                    : w2r[kkh];
                acc2 = __builtin_amdgcn_mfma_f32_16x16x32_bf16(wf, hfr[kkh], acc2, 0, 0, 0);
            }
            *(f32x4*)(op + g * 16 + l4 * 4) = acc2;
        }
    }
#undef LDG
}

extern "C" void kernel_launch(void* const* d_in, const int* in_sizes, int n_in,
                              void* d_out, int out_size, void* d_ws, size_t ws_size,
                              hipStream_t stream) {
    const float* x  = (const float*)d_in[0];
    const float* W1 = (const float*)d_in[1];
    const float* b1 = (const float*)d_in[2];
    const float* W2 = (const float*)d_in[3];
    const float* b2 = (const float*)d_in[4];
    float* out = (float*)d_out;

    unsigned short* w1f = (unsigned short*)d_ws;                 // 2 MiB
    unsigned short* w2f = w1f + (size_t)S_ * 8 * 8 * 64 * 8;     // 2 MiB (total = 4 MiB)

    pack_w1<<<S_ * 8, 256, 0, stream>>>(W1, w1f);
    pack_w2<<<S_ * 4, 256, 0, stream>>>(W2, w2f);
    subband_fused_kernel<<<256, 512, 0, stream>>>(x, w1f, w2f, b1, b2, out);
}

// Round 18
// 70.726 us; speedup vs baseline: 1.1662x; 1.0251x over previous
//
#include <hip/hip_runtime.h>
#include <hip/hip_bf16.h>

#define B_   4096
#define S_   32
#define IN_  256
#define H_   128
#define OUT_ 256

typedef __attribute__((ext_vector_type(8))) short bf16x8;
typedef __attribute__((ext_vector_type(4))) float f32x4;
typedef unsigned long long ull;

__device__ __forceinline__ unsigned short f2bf(float f) {
    union { float f; unsigned u; } v; v.f = f;
    unsigned r = v.u + 0x7FFFu + ((v.u >> 16) & 1u);   // RNE
    return (unsigned short)(r >> 16);
}
__device__ __forceinline__ unsigned cvt_pk(float lo, float hi) {
    unsigned r;
    asm("v_cvt_pk_bf16_f32 %0, %1, %2" : "=v"(r) : "v"(lo), "v"(hi));
    return r;
}

// Merged weight packer (one launch).
// blocks [0,256):   W1 [S][IN(k)][H] -> w1f[s][kk=8][hf=8][lane][8]
//                   lane: h-row = hf*16+(l&15), k = kk*32+(l>>4)*8+j
// blocks [256,384): W2 [S][H(k)][OUT] -> w2f[s][g=16][kkh=4][lane][8]
//                   lane: o-row = g*16+(l&15), h = kkh*32+(l>>4)*8+j
__global__ __launch_bounds__(256) void pack_both(const float* __restrict__ W1,
                                                 const float* __restrict__ W2,
                                                 unsigned short* __restrict__ w1f,
                                                 unsigned short* __restrict__ w2f) {
    __shared__ float tile[32][257];
    const int bid = blockIdx.x;
    const int t = threadIdx.x;
    if (bid < 256) {
        const int s = bid >> 3, kk = bid & 7;
#pragma unroll
        for (int i = 0; i < 16; ++i) {
            int idx = t + i * 256;
            int kl = idx >> 7, h = idx & 127;
            tile[kl][h] = W1[((size_t)s * IN_ + kk * 32 + kl) * H_ + h];
        }
        __syncthreads();
#pragma unroll
        for (int rep = 0; rep < 2; ++rep) {
            int idx = t + rep * 256;
            int hf = idx >> 6, l = idx & 63, l15 = l & 15, l4 = l >> 4;
            unsigned short o8[8];
#pragma unroll
            for (int j = 0; j < 8; ++j) o8[j] = f2bf(tile[l4 * 8 + j][hf * 16 + l15]);
            *(bf16x8*)(w1f + (((size_t)(s * 8 + kk) * 8 + hf) * 64 + l) * 8) = *(bf16x8*)o8;
        }
    } else {
        const int rel = bid - 256, s = rel >> 2, kkh = rel & 3;
#pragma unroll
        for (int i = 0; i < 32; ++i) {
            int idx = t + i * 256;
            int kl = idx >> 8, o = idx & 255;
            tile[kl][o] = W2[((size_t)s * H_ + kkh * 32 + kl) * OUT_ + o];
        }
        __syncthreads();
#pragma unroll
        for (int rep = 0; rep < 4; ++rep) {
            int idx = t + rep * 256;
            int g = idx >> 6, l = idx & 63, l15 = l & 15, l4 = l >> 4;
            unsigned short o8[8];
#pragma unroll
            for (int j = 0; j < 8; ++j) o8[j] = f2bf(tile[l4 * 8 + j][g * 16 + l15]);
            *(bf16x8*)(w2f + (((size_t)(s * 16 + g) * 4 + kkh) * 64 + l) * 8) = *(bf16x8*)o8;
        }
    }
}

// Weights-stationary fused MLP, fragment-major LDS, chunk-major XCD mapping.
// R18 = R15 (proven 72.5us) + merged pack launch + setprio around MFMA
// clusters (waves are independent after the single barrier -> T5's regime).
// Depth-1 x prefetch only: 64 in-flight asm-load VGPRs is the proven-safe
// envelope; depth-2 (R17) caused allocator spill of in-flight regs -> fault.
__global__ __launch_bounds__(512) void subband_fused_kernel(
        const float* __restrict__ x,
        const unsigned short* __restrict__ w1f,
        const unsigned short* __restrict__ w2f,
        const float* __restrict__ b1,
        const float* __restrict__ b2,
        float* __restrict__ out) {
    __shared__ __align__(16) unsigned char lds[161280];
    unsigned char* w1l = lds;
    unsigned char* w2l = lds + 65536;
    unsigned char* repb = lds + 126976;
    float* b1l = (float*)(lds + 159744);
    float* b2l = (float*)(lds + 160256);

    const int bid = blockIdx.x;
    const int s     = bid >> 3;                // subband
    const int chunk = bid & 7;                 // row-chunk == XCD id (dense per-XCD stream)
    const int tid = threadIdx.x;
    const int w = tid >> 6, l = tid & 63, l15 = l & 15, l4 = l >> 4;
    unsigned char* rep = repb + w * 4096;
    const int rw = chunk * 512 + w * 64;

#define LDG(dst, p) asm volatile("global_load_dwordx4 %0, %1, off" : "=v"(dst) : "v"(p))

    // ---- issue tile-0 x loads first ----
    f32x4 v[16];
    {
        const float* xr = x + ((size_t)(rw + l15) * S_ + s) * IN_ + l4 * 8;
#pragma unroll
        for (int kk = 0; kk < 8; ++kk) {
            LDG(v[2 * kk],     xr + kk * 32);
            LDG(v[2 * kk + 1], xr + kk * 32 + 4);
        }
    }

    // ---- stage weights: linear coalesced copies ----
    const unsigned char* w1src = (const unsigned char*)(w1f + (size_t)s * 32768);
#pragma unroll
    for (int i = 0; i < 8; ++i)
        *(bf16x8*)(w1l + tid * 16 + i * 8192) = *(const bf16x8*)(w1src + tid * 16 + i * 8192);
    const unsigned char* w2src = (const unsigned char*)(w2f + (size_t)s * 32768);
#pragma unroll
    for (int i = 0; i < 7; ++i)
        *(bf16x8*)(w2l + tid * 16 + i * 8192) = *(const bf16x8*)(w2src + tid * 16 + i * 8192);
    if (tid < 256)
        *(bf16x8*)(w2l + tid * 16 + 57344) = *(const bf16x8*)(w2src + tid * 16 + 57344);

    bf16x8 w2r[4];
#pragma unroll
    for (int kkh = 0; kkh < 4; ++kkh)
        w2r[kkh] = *(const bf16x8*)(w2src + (((size_t)15 * 4 + kkh) * 64 + l) * 16);

    if (tid < 128)      b1l[tid]       = b1[s * H_ + tid];
    else if (tid < 384) b2l[tid - 128] = b2[s * OUT_ + (tid - 128)];

    __syncthreads();                           // the ONLY barrier

    float* opbase = out + ((size_t)(rw + l15) * S_ + s) * OUT_;

#pragma unroll 1
    for (int t = 0; t < 4; ++t) {
        // ---- tile-top wait (R15-proven full drain) ----
        asm volatile("s_waitcnt vmcnt(0)"
            : "+v"(v[0]), "+v"(v[1]), "+v"(v[2]), "+v"(v[3]),
              "+v"(v[4]), "+v"(v[5]), "+v"(v[6]), "+v"(v[7]),
              "+v"(v[8]), "+v"(v[9]), "+v"(v[10]), "+v"(v[11]),
              "+v"(v[12]), "+v"(v[13]), "+v"(v[14]), "+v"(v[15]) :: "memory");
        __builtin_amdgcn_sched_barrier(0);

        // ---- convert to B-fragments: lane m = l15, k = kk*32 + l4*8 + j ----
        bf16x8 xb[8];
#pragma unroll
        for (int kk = 0; kk < 8; ++kk) {
            union { unsigned u[4]; bf16x8 b; } p;
            p.u[0] = cvt_pk(v[2 * kk][0],     v[2 * kk][1]);
            p.u[1] = cvt_pk(v[2 * kk][2],     v[2 * kk][3]);
            p.u[2] = cvt_pk(v[2 * kk + 1][0], v[2 * kk + 1][1]);
            p.u[3] = cvt_pk(v[2 * kk + 1][2], v[2 * kk + 1][3]);
            xb[kk] = p.b;
        }

        // ---- issue next tile's x loads ----
        if (t < 3) {
            const float* xr = x + ((size_t)(rw + (t + 1) * 16 + l15) * S_ + s) * IN_ + l4 * 8;
#pragma unroll
            for (int kk = 0; kk < 8; ++kk) {
                LDG(v[2 * kk],     xr + kk * 32);
                LDG(v[2 * kk + 1], xr + kk * 32 + 4);
            }
        }

        // ---- layer 1 swapped: acc1[hf] holds h = hf*16 + l4*4 + i, m = l15 ----
        f32x4 acc1[8];
#pragma unroll
        for (int hf = 0; hf < 8; ++hf) {
            const float4 bv = *(const float4*)(b1l + hf * 16 + l4 * 4);
            acc1[hf][0] = bv.x; acc1[hf][1] = bv.y; acc1[hf][2] = bv.z; acc1[hf][3] = bv.w;
        }
        __builtin_amdgcn_s_setprio(1);
#pragma unroll
        for (int kk = 0; kk < 8; ++kk)
#pragma unroll
            for (int hf = 0; hf < 8; ++hf) {
                const bf16x8 wf = *(const bf16x8*)(w1l + ((kk * 8 + hf) * 64 + l) * 16);
                acc1[hf] = __builtin_amdgcn_mfma_f32_16x16x32_bf16(wf, xb[kk], acc1[hf], 0, 0, 0);
            }
        __builtin_amdgcn_s_setprio(0);

        // ---- relu + repack -> fragment-major rep ----
#pragma unroll
        for (int hf = 0; hf < 8; ++hf) {
            unsigned p0 = cvt_pk(fmaxf(acc1[hf][0], 0.f), fmaxf(acc1[hf][1], 0.f));
            unsigned p1 = cvt_pk(fmaxf(acc1[hf][2], 0.f), fmaxf(acc1[hf][3], 0.f));
            ull p = (ull)p0 | ((ull)p1 << 32);
            const int kkh = hf >> 1;
            const int l4p = ((hf & 1) << 1) | (l4 >> 1);
            *(ull*)(rep + kkh * 1024 + (l4p * 16 + l15) * 16 + ((l4 & 1) * 8)) = p;
        }
        asm volatile("s_waitcnt lgkmcnt(0)" ::: "memory");
        __builtin_amdgcn_sched_barrier(0);

        bf16x8 hfr[4];
#pragma unroll
        for (int kkh = 0; kkh < 4; ++kkh)
            hfr[kkh] = *(const bf16x8*)(rep + kkh * 1024 + l * 16);

        // ---- layer 2 swapped: D2[o][m]; o = g*16 + l4*4 + i, m = l15 ----
        float* op = opbase + (size_t)t * 16 * S_ * OUT_;
#pragma unroll
        for (int g = 0; g < 16; ++g) {
            const float4 bv = *(const float4*)(b2l + g * 16 + l4 * 4);
            f32x4 acc2;
            acc2[0] = bv.x; acc2[1] = bv.y; acc2[2] = bv.z; acc2[3] = bv.w;
            __builtin_amdgcn_s_setprio(1);
#pragma unroll
            for (int kkh = 0; kkh < 4; ++kkh) {
                const bf16x8 wf = (g < 15)
                    ? *(const bf16x8*)(w2l + ((g * 4 + kkh) * 64 + l) * 16)
                    : w2r[kkh];
                acc2 = __builtin_amdgcn_mfma_f32_16x16x32_bf16(wf, hfr[kkh], acc2, 0, 0, 0);
            }
            __builtin_amdgcn_s_setprio(0);
            *(f32x4*)(op + g * 16 + l4 * 4) = acc2;
        }
    }
#undef LDG
}

extern "C" void kernel_launch(void* const* d_in, const int* in_sizes, int n_in,
                              void* d_out, int out_size, void* d_ws, size_t ws_size,
                              hipStream_t stream) {
    const float* x  = (const float*)d_in[0];
    const float* W1 = (const float*)d_in[1];
    const float* b1 = (const float*)d_in[2];
    const float* W2 = (const float*)d_in[3];
    const float* b2 = (const float*)d_in[4];
    float* out = (float*)d_out;

    unsigned short* w1f = (unsigned short*)d_ws;                 // 2 MiB
    unsigned short* w2f = w1f + (size_t)S_ * 8 * 8 * 64 * 8;     // 2 MiB (total = 4 MiB)

    pack_both<<<384, 256, 0, stream>>>(W1, W2, w1f, w2f);
    subband_fused_kernel<<<256, 512, 0, stream>>>(x, w1f, w2f, b1, b2, out);
}

// Round 19
// 67.365 us; speedup vs baseline: 1.2244x; 1.0499x over previous
//
#include <hip/hip_runtime.h>
#include <hip/hip_bf16.h>

#define B_   4096
#define S_   32
#define IN_  256
#define H_   128
#define OUT_ 256

typedef __attribute__((ext_vector_type(8))) short bf16x8;
typedef __attribute__((ext_vector_type(4))) float f32x4;
typedef unsigned long long ull;

__device__ __forceinline__ unsigned short f2bf(float f) {
    union { float f; unsigned u; } v; v.f = f;
    unsigned r = v.u + 0x7FFFu + ((v.u >> 16) & 1u);   // RNE
    return (unsigned short)(r >> 16);
}
__device__ __forceinline__ unsigned cvt_pk(float lo, float hi) {
    unsigned r;
    asm("v_cvt_pk_bf16_f32 %0, %1, %2" : "=v"(r) : "v"(lo), "v"(hi));
    return r;
}

// Merged weight packer (one launch).
// blocks [0,256):   W1 [S][IN(k)][H] -> w1f[s][kk=8][hf=8][lane][8]
// blocks [256,384): W2 [S][H(k)][OUT] -> w2f[s][g=16][kkh=4][lane][8]
__global__ __launch_bounds__(256) void pack_both(const float* __restrict__ W1,
                                                 const float* __restrict__ W2,
                                                 unsigned short* __restrict__ w1f,
                                                 unsigned short* __restrict__ w2f) {
    __shared__ float tile[32][257];
    const int bid = blockIdx.x;
    const int t = threadIdx.x;
    if (bid < 256) {
        const int s = bid >> 3, kk = bid & 7;
#pragma unroll
        for (int i = 0; i < 16; ++i) {
            int idx = t + i * 256;
            int kl = idx >> 7, h = idx & 127;
            tile[kl][h] = W1[((size_t)s * IN_ + kk * 32 + kl) * H_ + h];
        }
        __syncthreads();
#pragma unroll
        for (int rep = 0; rep < 2; ++rep) {
            int idx = t + rep * 256;
            int hf = idx >> 6, l = idx & 63, l15 = l & 15, l4 = l >> 4;
            unsigned short o8[8];
#pragma unroll
            for (int j = 0; j < 8; ++j) o8[j] = f2bf(tile[l4 * 8 + j][hf * 16 + l15]);
            *(bf16x8*)(w1f + (((size_t)(s * 8 + kk) * 8 + hf) * 64 + l) * 8) = *(bf16x8*)o8;
        }
    } else {
        const int rel = bid - 256, s = rel >> 2, kkh = rel & 3;
#pragma unroll
        for (int i = 0; i < 32; ++i) {
            int idx = t + i * 256;
            int kl = idx >> 8, o = idx & 255;
            tile[kl][o] = W2[((size_t)s * H_ + kkh * 32 + kl) * OUT_ + o];
        }
        __syncthreads();
#pragma unroll
        for (int rep = 0; rep < 4; ++rep) {
            int idx = t + rep * 256;
            int g = idx >> 6, l = idx & 63, l15 = l & 15, l4 = l >> 4;
            unsigned short o8[8];
#pragma unroll
            for (int j = 0; j < 8; ++j) o8[j] = f2bf(tile[l4 * 8 + j][g * 16 + l15]);
            *(bf16x8*)(w2f + (((size_t)(s * 16 + g) * 4 + kkh) * 64 + l) * 8) = *(bf16x8*)o8;
        }
    }
}

// Weights-stationary fused MLP, fragment-major LDS, chunk-major XCD mapping.
// R19 vs R18: 2-tile weight-read PAIRING — each LDS weight fragment read once
// per 32 rows (2 MFMAs per ds_read_b128), halving the dominant LDS traffic.
// Next-pair x loads issue during L2-pair (xb/acc1 dead) so in-flight asm
// VGPRs never coexist with peak pressure.
__global__ __launch_bounds__(512) void subband_fused_kernel(
        const float* __restrict__ x,
        const unsigned short* __restrict__ w1f,
        const unsigned short* __restrict__ w2f,
        const float* __restrict__ b1,
        const float* __restrict__ b2,
        float* __restrict__ out) {
    __shared__ __align__(16) unsigned char lds[161280];
    unsigned char* w1l = lds;
    unsigned char* w2l = lds + 65536;
    unsigned char* repb = lds + 126976;
    float* b1l = (float*)(lds + 159744);
    float* b2l = (float*)(lds + 160256);

    const int bid = blockIdx.x;
    const int s     = bid >> 3;                // subband
    const int chunk = bid & 7;                 // row-chunk == XCD id (dense per-XCD stream)
    const int tid = threadIdx.x;
    const int w = tid >> 6, l = tid & 63, l15 = l & 15, l4 = l >> 4;
    unsigned char* rep = repb + w * 4096;
    const int rw = chunk * 512 + w * 64;

#define LDG(dst, p) asm volatile("global_load_dwordx4 %0, %1, off" : "=v"(dst) : "v"(p))
#define WAITV0                                                                   \
    asm volatile("s_waitcnt vmcnt(0)"                                            \
        : "+v"(v[0]), "+v"(v[1]), "+v"(v[2]), "+v"(v[3]),                        \
          "+v"(v[4]), "+v"(v[5]), "+v"(v[6]), "+v"(v[7]),                        \
          "+v"(v[8]), "+v"(v[9]), "+v"(v[10]), "+v"(v[11]),                      \
          "+v"(v[12]), "+v"(v[13]), "+v"(v[14]), "+v"(v[15]) :: "memory")
#define ISSUE_X(ROW0)                                                            \
    do {                                                                         \
        const float* xr_ = x + ((size_t)((ROW0) + l15) * S_ + s) * IN_ + l4 * 8; \
        _Pragma("unroll")                                                        \
        for (int kk = 0; kk < 8; ++kk) {                                         \
            LDG(v[2 * kk],     xr_ + kk * 32);                                   \
            LDG(v[2 * kk + 1], xr_ + kk * 32 + 4);                               \
        }                                                                        \
    } while (0)
#define CVT_XB(XB)                                                               \
    do {                                                                         \
        _Pragma("unroll")                                                        \
        for (int kk = 0; kk < 8; ++kk) {                                         \
            union { unsigned u[4]; bf16x8 b; } p;                                \
            p.u[0] = cvt_pk(v[2 * kk][0],     v[2 * kk][1]);                     \
            p.u[1] = cvt_pk(v[2 * kk][2],     v[2 * kk][3]);                     \
            p.u[2] = cvt_pk(v[2 * kk + 1][0], v[2 * kk + 1][1]);                 \
            p.u[3] = cvt_pk(v[2 * kk + 1][2], v[2 * kk + 1][3]);                 \
            XB[kk] = p.b;                                                        \
        }                                                                        \
    } while (0)
#define REPACK(ACC, HFR)                                                         \
    do {                                                                         \
        _Pragma("unroll")                                                        \
        for (int hf = 0; hf < 8; ++hf) {                                         \
            unsigned p0 = cvt_pk(fmaxf(ACC[hf][0], 0.f), fmaxf(ACC[hf][1], 0.f));\
            unsigned p1 = cvt_pk(fmaxf(ACC[hf][2], 0.f), fmaxf(ACC[hf][3], 0.f));\
            ull p = (ull)p0 | ((ull)p1 << 32);                                   \
            const int kkh = hf >> 1;                                             \
            const int l4p = ((hf & 1) << 1) | (l4 >> 1);                         \
            *(ull*)(rep + kkh * 1024 + (l4p * 16 + l15) * 16 + ((l4 & 1) * 8)) = p; \
        }                                                                        \
        asm volatile("s_waitcnt lgkmcnt(0)" ::: "memory");                       \
        __builtin_amdgcn_sched_barrier(0);                                       \
        _Pragma("unroll")                                                        \
        for (int kkh = 0; kkh < 4; ++kkh)                                        \
            HFR[kkh] = *(const bf16x8*)(rep + kkh * 1024 + l * 16);              \
        asm volatile("s_waitcnt lgkmcnt(0)" ::: "memory");                       \
        __builtin_amdgcn_sched_barrier(0);                                       \
    } while (0)

    // ---- prologue: issue tile-0 x loads ----
    f32x4 v[16];
    ISSUE_X(rw);

    // ---- stage weights: linear coalesced copies ----
    const unsigned char* w1src = (const unsigned char*)(w1f + (size_t)s * 32768);
#pragma unroll
    for (int i = 0; i < 8; ++i)
        *(bf16x8*)(w1l + tid * 16 + i * 8192) = *(const bf16x8*)(w1src + tid * 16 + i * 8192);
    const unsigned char* w2src = (const unsigned char*)(w2f + (size_t)s * 32768);
#pragma unroll
    for (int i = 0; i < 7; ++i)
        *(bf16x8*)(w2l + tid * 16 + i * 8192) = *(const bf16x8*)(w2src + tid * 16 + i * 8192);
    if (tid < 256)
        *(bf16x8*)(w2l + tid * 16 + 57344) = *(const bf16x8*)(w2src + tid * 16 + 57344);

    bf16x8 w2r[4];
#pragma unroll
    for (int kkh = 0; kkh < 4; ++kkh)
        w2r[kkh] = *(const bf16x8*)(w2src + (((size_t)15 * 4 + kkh) * 64 + l) * 16);

    if (tid < 128)      b1l[tid]       = b1[s * H_ + tid];
    else if (tid < 384) b2l[tid - 128] = b2[s * OUT_ + (tid - 128)];

    __syncthreads();                           // the ONLY barrier

    float* opbase = out + ((size_t)(rw + l15) * S_ + s) * OUT_;

// One pair of tiles (T, T+1). DO_NEXT: prefetch tile T+2 during L2 phase.
#define PAIR_BODY(T, DO_NEXT)                                                    \
do {                                                                             \
    WAITV0;                                                                      \
    __builtin_amdgcn_sched_barrier(0);                                           \
    bf16x8 xbA[8], xbB[8];                                                       \
    CVT_XB(xbA);                                                                 \
    ISSUE_X(rw + ((T) + 1) * 16);                                                \
    WAITV0;                                                                      \
    __builtin_amdgcn_sched_barrier(0);                                           \
    CVT_XB(xbB);                                                                 \
    f32x4 acc1A[8], acc1B[8];                                                    \
    _Pragma("unroll")                                                            \
    for (int hf = 0; hf < 8; ++hf) {                                             \
        const float4 bv = *(const float4*)(b1l + hf * 16 + l4 * 4);              \
        acc1A[hf][0] = bv.x; acc1A[hf][1] = bv.y;                                \
        acc1A[hf][2] = bv.z; acc1A[hf][3] = bv.w;                                \
        acc1B[hf] = acc1A[hf];                                                   \
    }                                                                            \
    __builtin_amdgcn_s_setprio(1);                                               \
    _Pragma("unroll")                                                            \
    for (int kk = 0; kk < 8; ++kk)                                               \
        _Pragma("unroll")                                                        \
        for (int hf = 0; hf < 8; ++hf) {                                         \
            const bf16x8 wf = *(const bf16x8*)(w1l + ((kk * 8 + hf) * 64 + l) * 16); \
            acc1A[hf] = __builtin_amdgcn_mfma_f32_16x16x32_bf16(                 \
                wf, xbA[kk], acc1A[hf], 0, 0, 0);                                \
            acc1B[hf] = __builtin_amdgcn_mfma_f32_16x16x32_bf16(                 \
                wf, xbB[kk], acc1B[hf], 0, 0, 0);                                \
        }                                                                        \
    __builtin_amdgcn_s_setprio(0);                                               \
    bf16x8 hfrA[4], hfrB[4];                                                     \
    REPACK(acc1A, hfrA);                                                         \
    REPACK(acc1B, hfrB);                                                         \
    if (DO_NEXT) ISSUE_X(rw + ((T) + 2) * 16);                                   \
    float* opA = opbase + (size_t)(T) * 16 * S_ * OUT_;                          \
    float* opB = opA + (size_t)16 * S_ * OUT_;                                   \
    _Pragma("unroll")                                                            \
    for (int g = 0; g < 16; ++g) {                                               \
        const float4 bv = *(const float4*)(b2l + g * 16 + l4 * 4);               \
        f32x4 accA, accB;                                                        \
        accA[0] = bv.x; accA[1] = bv.y; accA[2] = bv.z; accA[3] = bv.w;          \
        accB = accA;                                                             \
        __builtin_amdgcn_s_setprio(1);                                           \
        _Pragma("unroll")                                                        \
        for (int kkh = 0; kkh < 4; ++kkh) {                                      \
            const bf16x8 wf = (g < 15)                                           \
                ? *(const bf16x8*)(w2l + ((g * 4 + kkh) * 64 + l) * 16)          \
                : w2r[kkh];                                                      \
            accA = __builtin_amdgcn_mfma_f32_16x16x32_bf16(wf, hfrA[kkh], accA, 0, 0, 0); \
            accB = __builtin_amdgcn_mfma_f32_16x16x32_bf16(wf, hfrB[kkh], accB, 0, 0, 0); \
        }                                                                        \
        __builtin_amdgcn_s_setprio(0);                                           \
        *(f32x4*)(opA + g * 16 + l4 * 4) = accA;                                 \
        *(f32x4*)(opB + g * 16 + l4 * 4) = accB;                                 \
    }                                                                            \
} while (0)

    PAIR_BODY(0, 1);
    PAIR_BODY(2, 0);

#undef PAIR_BODY
#undef REPACK
#undef CVT_XB
#undef ISSUE_X
#undef WAITV0
#undef LDG
}

extern "C" void kernel_launch(void* const* d_in, const int* in_sizes, int n_in,
                              void* d_out, int out_size, void* d_ws, size_t ws_size,
                              hipStream_t stream) {
    const float* x  = (const float*)d_in[0];
    const float* W1 = (const float*)d_in[1];
    const float* b1 = (const float*)d_in[2];
    const float* W2 = (const float*)d_in[3];
    const float* b2 = (const float*)d_in[4];
    float* out = (float*)d_out;

    unsigned short* w1f = (unsigned short*)d_ws;                 // 2 MiB
    unsigned short* w2f = w1f + (size_t)S_ * 8 * 8 * 64 * 8;     // 2 MiB (total = 4 MiB)

    pack_both<<<384, 256, 0, stream>>>(W1, W2, w1f, w2f);
    subband_fused_kernel<<<256, 512, 0, stream>>>(x, w1f, w2f, b1, b2, out);
}